// Round 2
// baseline (739.362 us; speedup 1.0000x reference)
//
#include <hip/hip_runtime.h>

// SpiralConv: g[t] = a*g[t-1] + init*x[t], g[-1]=last_conv; out = Re(g).
//   a = p/|p| * exp(-|p|).
// Fused single-kernel hierarchical chunked scan (CHUNK=16) with a MANUAL
// device-scope grid barrier (no cooperative launch — cg::grid_sync proved
// unreliable under the harness's graph capture):
//   phase1: per (b,chunk,d) local scan, zero init             -> S
//   phase2: (first 128 blocks) per (b,seg,d) scan 32 chunks   -> R, T
//   phase3: segC from T+lc in-register, C0 = R + q^rel*segC, replay chunk -> out
// Grid = 1024 blocks x 256 thr = exactly 4 blocks/CU (launch_bounds(256,4),
// LDS=0) -> all blocks co-resident -> spin barrier cannot deadlock.
// Barrier counters sit in workspace, zeroed by hipMemsetAsync each launch.

#define BB 4
#define LL 4096
#define DD 1024
#define CHUNK 16
#define KK 256     // LL/CHUNK
#define SEG 32     // chunks per segment
#define NSEG 8     // KK/SEG
#define NBLK 1024u

__device__ __forceinline__ void phazor_of(float pr, float pi, float& ar, float& ai) {
    float mag = sqrtf(pr * pr + pi * pi);
    float s = expf(-mag) / mag;   // phazor = p/|p| * exp(-|p|)
    ar = pr * s;
    ai = pi * s;
}

__device__ __forceinline__ void csq(float& r, float& i) {
    float nr = r * r - i * i;
    i = 2.f * r * i;
    r = nr;
}

// Device-scope grid barrier. ctr must be zero at kernel start and is used ONCE.
__device__ __forceinline__ void grid_barrier(unsigned* ctr) {
    __threadfence();                 // release: my writes -> device scope
    __syncthreads();                 // whole block has arrived + fenced
    if (threadIdx.x == 0) {
        __hip_atomic_fetch_add(ctr, 1u, __ATOMIC_ACQ_REL, __HIP_MEMORY_SCOPE_AGENT);
        long long spins = 0;
        while (__hip_atomic_load(ctr, __ATOMIC_ACQUIRE, __HIP_MEMORY_SCOPE_AGENT) < NBLK) {
            __builtin_amdgcn_s_sleep(2);
            if (++spins > (1LL << 27)) break;   // safety valve: never hang the bench
        }
    }
    __syncthreads();
    __threadfence();                 // acquire: invalidate stale cached lines
}

__global__ __launch_bounds__(256, 4) void spiral_fused(
    const float* __restrict__ x,
    const float* __restrict__ p_re, const float* __restrict__ p_im,
    const float* __restrict__ in_re, const float* __restrict__ in_im,
    const float* __restrict__ lc_re, const float* __restrict__ lc_im,
    float2* __restrict__ S, float2* __restrict__ R, float2* __restrict__ T,
    unsigned* __restrict__ bar,
    float* __restrict__ out)
{
    const int tid = blockIdx.x * 256 + threadIdx.x;
    const int dq = tid & (DD / 4 - 1);
    const int k  = (tid >> 8) & (KK - 1);
    const int b  = tid >> 16;
    const int d0 = dq * 4;

    // phase-invariant constants: a = phazor(p), binit
    float ar[4], ai[4], br[4], bi[4];
    {
        float4 prv = *(const float4*)(p_re + d0);
        float4 piv = *(const float4*)(p_im + d0);
        float4 brv = *(const float4*)(in_re + d0);
        float4 biv = *(const float4*)(in_im + d0);
        float prs[4] = {prv.x, prv.y, prv.z, prv.w};
        float pis[4] = {piv.x, piv.y, piv.z, piv.w};
        br[0] = brv.x; br[1] = brv.y; br[2] = brv.z; br[3] = brv.w;
        bi[0] = biv.x; bi[1] = biv.y; bi[2] = biv.z; bi[3] = biv.w;
#pragma unroll
        for (int q = 0; q < 4; ++q) phazor_of(prs[q], pis[q], ar[q], ai[q]);
    }

    const size_t xbase = (size_t)(b * LL + k * CHUNK) * DD + d0;

    // ---------------- phase 1: chunk-local scan, zero init ----------------
    {
        const float* xp = x + xbase;
        float4 xv[16];
#pragma unroll
        for (int j = 0; j < 16; ++j)
            xv[j] = *(const float4*)(xp + (size_t)j * DD);

        float sr[4] = {0.f, 0.f, 0.f, 0.f};
        float si[4] = {0.f, 0.f, 0.f, 0.f};
#pragma unroll
        for (int j = 0; j < 16; ++j) {
            float xs[4] = {xv[j].x, xv[j].y, xv[j].z, xv[j].w};
#pragma unroll
            for (int q = 0; q < 4; ++q) {
                float nr = fmaf(ar[q], sr[q], fmaf(-ai[q], si[q], br[q] * xs[q]));
                float ni = fmaf(ar[q], si[q], fmaf( ai[q], sr[q], bi[q] * xs[q]));
                sr[q] = nr; si[q] = ni;
            }
        }
        float4* Sp = (float4*)(S + ((size_t)(b * KK + k) * DD + d0));
        Sp[0] = make_float4(sr[0], si[0], sr[1], si[1]);
        Sp[1] = make_float4(sr[2], si[2], sr[3], si[3]);
    }

    grid_barrier(bar + 0);

    // ---------------- phase 2: segment-relative scans (first 128 blocks) ----------------
    if (blockIdx.x < 128) {
        const int gt  = tid;              // 0..32767 = BB*NSEG*DD
        const int d   = gt & (DD - 1);
        const int seg = (gt >> 10) & (NSEG - 1);
        const int bb  = gt >> 13;

        float qr, qi;
        phazor_of(p_re[d], p_im[d], qr, qi);
#pragma unroll
        for (int i = 0; i < 4; ++i) csq(qr, qi);      // q = a^16

        const int kk0 = seg * SEG;
        const float2* Sc = S + ((size_t)bb * KK * DD + d);
        float2*       Rc = R + ((size_t)bb * KK * DD + d);

        float2 buf[8];
#pragma unroll
        for (int j = 0; j < 8; ++j) buf[j] = Sc[(size_t)(kk0 + j) * DD];

        float cr = 0.f, ci = 0.f;
        for (int i = 0; i < SEG; i += 8) {
#pragma unroll
            for (int j = 0; j < 8; ++j) {
                Rc[(size_t)(kk0 + i + j) * DD] = make_float2(cr, ci);
                float2 s = buf[j];
                int kn = i + j + 8;
                buf[j] = Sc[(size_t)(kk0 + (kn < SEG ? kn : SEG - 1)) * DD];
                float nr = fmaf(qr, cr, fmaf(-qi, ci, s.x));
                float ni = fmaf(qr, ci, fmaf( qi, cr, s.y));
                cr = nr; ci = ni;
            }
        }
        T[((size_t)bb * NSEG + seg) * DD + d] = make_float2(cr, ci);
    }

    grid_barrier(bar + 32);   // separate cache line, used once

    // ---------------- phase 3: segment init + combine + replay ----------------
    const int rel  = k & (SEG - 1);   // wave-uniform
    const int seg3 = k >> 5;          // wave-uniform

    float gr[4], gi[4];
    {
        float4 lrv = *(const float4*)(lc_re + b * DD + d0);
        float4 liv = *(const float4*)(lc_im + b * DD + d0);
        gr[0] = lrv.x; gr[1] = lrv.y; gr[2] = lrv.z; gr[3] = lrv.w;
        gi[0] = liv.x; gi[1] = liv.y; gi[2] = liv.z; gi[3] = liv.w;
        float Qr[4], Qi[4];
#pragma unroll
        for (int q = 0; q < 4; ++q) {
            Qr[q] = ar[q]; Qi[q] = ai[q];
#pragma unroll
            for (int i = 0; i < 9; ++i) csq(Qr[q], Qi[q]);   // a^512
        }
        for (int s = 0; s < seg3; ++s) {                     // <=7 iters, uniform
            const float2* Tp = T + ((size_t)(b * NSEG + s) * DD + d0);
#pragma unroll
            for (int q = 0; q < 4; ++q) {
                float2 t = Tp[q];
                float nr = fmaf(Qr[q], gr[q], fmaf(-Qi[q], gi[q], t.x));
                float ni = fmaf(Qr[q], gi[q], fmaf( Qi[q], gr[q], t.y));
                gr[q] = nr; gi[q] = ni;
            }
        }
    }

    // C0 = R + (a^16)^rel * g
    float cr[4], ci[4];
    {
        const float2* Rp = R + ((size_t)(b * KK + k) * DD + d0);
#pragma unroll
        for (int q = 0; q < 4; ++q) {
            float qdr = ar[q], qdi = ai[q];
#pragma unroll
            for (int i = 0; i < 4; ++i) csq(qdr, qdi);       // a^16
            float pr = 1.f, pi = 0.f;
            float bpr = qdr, bpi = qdi;
#pragma unroll
            for (int bit = 0; bit < 5; ++bit) {              // (a^16)^rel
                if ((rel >> bit) & 1) {
                    float nr = pr * bpr - pi * bpi;
                    pi = pr * bpi + pi * bpr;
                    pr = nr;
                }
                csq(bpr, bpi);
            }
            float2 r = Rp[q];
            cr[q] = r.x + pr * gr[q] - pi * gi[q];
            ci[q] = r.y + pr * gi[q] + pi * gr[q];
        }
    }

    // replay chunk (x re-read hits L2/L3: working set is Infinity-Cache-resident)
    {
        const float* xp = x + xbase;
        float* op = out + xbase;
        float4 xv[16];
#pragma unroll
        for (int j = 0; j < 16; ++j)
            xv[j] = *(const float4*)(xp + (size_t)j * DD);
#pragma unroll
        for (int j = 0; j < 16; ++j) {
            float xs[4] = {xv[j].x, xv[j].y, xv[j].z, xv[j].w};
            float os[4];
#pragma unroll
            for (int q = 0; q < 4; ++q) {
                float nr = fmaf(ar[q], cr[q], fmaf(-ai[q], ci[q], br[q] * xs[q]));
                float ni = fmaf(ar[q], ci[q], fmaf( ai[q], cr[q], bi[q] * xs[q]));
                cr[q] = nr; ci[q] = ni;
                os[q] = nr;
            }
            *(float4*)(op + (size_t)j * DD) = make_float4(os[0], os[1], os[2], os[3]);
        }
    }
}

extern "C" void kernel_launch(void* const* d_in, const int* in_sizes, int n_in,
                              void* d_out, int out_size, void* d_ws, size_t ws_size,
                              hipStream_t stream) {
    const float* x      = (const float*)d_in[0];
    const float* p_re   = (const float*)d_in[1];
    const float* p_im   = (const float*)d_in[2];
    const float* pin_re = (const float*)d_in[3];
    const float* pin_im = (const float*)d_in[4];
    const float* lc_re  = (const float*)d_in[5];
    const float* lc_im  = (const float*)d_in[6];
    float* out = (float*)d_out;

    char* ws = (char*)d_ws;
    float2*   S   = (float2*)(ws);                              // 8 MiB
    float2*   R   = (float2*)(ws + (size_t)8  * 1024 * 1024);   // 8 MiB
    float2*   T   = (float2*)(ws + (size_t)16 * 1024 * 1024);   // 256 KiB
    unsigned* bar = (unsigned*)(ws + (size_t)17 * 1024 * 1024); // 2 counters

    // zero the barrier counters (stream op, graph-capturable)
    hipMemsetAsync(bar, 0, 256, stream);

    spiral_fused<<<dim3(NBLK), dim3(256), 0, stream>>>(
        x, p_re, p_im, pin_re, pin_im, lc_re, lc_im, S, R, T, bar, out);
}

// Round 3
// 159.650 us; speedup vs baseline: 4.6311x; 4.6311x over previous
//
#include <hip/hip_runtime.h>

// SpiralConv: g[t] = a*g[t-1] + init*x[t], g[-1]=last_conv; out = Re(g).
//   a = p/|p| * exp(-|p|).
// Fused single-kernel hierarchical chunked scan (CHUNK=16) with a FENCE-FREE
// grid barrier:
//  - All cross-block data (S, R, T) moves via relaxed AGENT-scope 8B atomic
//    load/store (sc1 -> coherence point, bypasses non-coherent per-XCD L2).
//    So the barrier needs NO cache maintenance: no __threadfence, no acquire
//    in the spin loop (round-2's 650us barrier cost was an agent-acquire
//    L2-invalidate storm).
//  - Barrier = grouped arrival counters (32 groups x 32 blocks) + global
//    counter, relaxed atomics only, s_sleep polling, bounded spin.
//  - x / out use normal cached paths; since no L2 invalidate ever runs,
//    phase 3's x re-read hits the block's own L2 (same chunk as phase 1).
// Grid = 1024 blocks x 256 thr = exactly 4 blocks/CU (launch_bounds(256,4),
// LDS=0) -> all blocks co-resident -> spin barrier cannot deadlock.

#define BB 4
#define LL 4096
#define DD 1024
#define CHUNK 16
#define KK 256     // LL/CHUNK
#define SEG 32     // chunks per segment
#define NSEG 8     // KK/SEG
#define NBLK 1024u

__device__ __forceinline__ void phazor_of(float pr, float pi, float& ar, float& ai) {
    float mag = sqrtf(pr * pr + pi * pi);
    float s = expf(-mag) / mag;   // phazor = p/|p| * exp(-|p|)
    ar = pr * s;
    ai = pi * s;
}

__device__ __forceinline__ void csq(float& r, float& i) {
    float nr = r * r - i * i;
    i = 2.f * r * i;
    r = nr;
}

// coherence-point (sc1) 8-byte data movement: visible cross-XCD without fences
__device__ __forceinline__ void st8(float2* p, float2 v) {
    __hip_atomic_store(p, v, __ATOMIC_RELAXED, __HIP_MEMORY_SCOPE_AGENT);
}
__device__ __forceinline__ float2 ld8(const float2* p) {
    return __hip_atomic_load((float2*)p, __ATOMIC_RELAXED, __HIP_MEMORY_SCOPE_AGENT);
}

// Fence-free grid barrier. A = 32 group counters (128B apart), G = global.
// Counters must be zero at kernel start; each barrier uses its own set.
__device__ __forceinline__ void grid_barrier(unsigned* A, unsigned* G) {
    __syncthreads();   // emits s_waitcnt vmcnt(0): all sc1 stores are at L3
    if (threadIdx.x == 0) {
        const unsigned g = blockIdx.x >> 5;          // 32 blocks per group
        unsigned a = __hip_atomic_fetch_add(&A[g * 32], 1u,
                        __ATOMIC_RELAXED, __HIP_MEMORY_SCOPE_AGENT);
        if (a == 31u)
            __hip_atomic_fetch_add(G, 32u,
                        __ATOMIC_RELAXED, __HIP_MEMORY_SCOPE_AGENT);
        long long spins = 0;
        while (__hip_atomic_load(G, __ATOMIC_RELAXED,
                                 __HIP_MEMORY_SCOPE_AGENT) < NBLK) {
            __builtin_amdgcn_s_sleep(32);
            if (++spins > (1LL << 22)) break;   // never hang the bench
        }
    }
    __syncthreads();
}

__global__ __launch_bounds__(256, 4) void spiral_fused(
    const float* __restrict__ x,
    const float* __restrict__ p_re, const float* __restrict__ p_im,
    const float* __restrict__ in_re, const float* __restrict__ in_im,
    const float* __restrict__ lc_re, const float* __restrict__ lc_im,
    float2* __restrict__ S, float2* __restrict__ R, float2* __restrict__ T,
    unsigned* __restrict__ bar,
    float* __restrict__ out)
{
    const int tid = blockIdx.x * 256 + threadIdx.x;
    const int dq = tid & (DD / 4 - 1);
    const int k  = (tid >> 8) & (KK - 1);
    const int b  = tid >> 16;
    const int d0 = dq * 4;

    // phase-invariant constants: a = phazor(p), binit
    float ar[4], ai[4], br[4], bi[4];
    {
        float4 prv = *(const float4*)(p_re + d0);
        float4 piv = *(const float4*)(p_im + d0);
        float4 brv = *(const float4*)(in_re + d0);
        float4 biv = *(const float4*)(in_im + d0);
        float prs[4] = {prv.x, prv.y, prv.z, prv.w};
        float pis[4] = {piv.x, piv.y, piv.z, piv.w};
        br[0] = brv.x; br[1] = brv.y; br[2] = brv.z; br[3] = brv.w;
        bi[0] = biv.x; bi[1] = biv.y; bi[2] = biv.z; bi[3] = biv.w;
#pragma unroll
        for (int q = 0; q < 4; ++q) phazor_of(prs[q], pis[q], ar[q], ai[q]);
    }

    const size_t xbase = (size_t)(b * LL + k * CHUNK) * DD + d0;

    // ---------------- phase 1: chunk-local scan, zero init ----------------
    {
        const float* xp = x + xbase;
        float4 xv[16];
#pragma unroll
        for (int j = 0; j < 16; ++j)
            xv[j] = *(const float4*)(xp + (size_t)j * DD);

        float sr[4] = {0.f, 0.f, 0.f, 0.f};
        float si[4] = {0.f, 0.f, 0.f, 0.f};
#pragma unroll
        for (int j = 0; j < 16; ++j) {
            float xs[4] = {xv[j].x, xv[j].y, xv[j].z, xv[j].w};
#pragma unroll
            for (int q = 0; q < 4; ++q) {
                float nr = fmaf(ar[q], sr[q], fmaf(-ai[q], si[q], br[q] * xs[q]));
                float ni = fmaf(ar[q], si[q], fmaf( ai[q], sr[q], bi[q] * xs[q]));
                sr[q] = nr; si[q] = ni;
            }
        }
        float2* Sp = S + ((size_t)(b * KK + k) * DD + d0);
#pragma unroll
        for (int q = 0; q < 4; ++q)
            st8(Sp + q, make_float2(sr[q], si[q]));
    }

    grid_barrier(bar, bar + 1024);

    // ---------------- phase 2: segment-relative scans (first 128 blocks) ----------------
    if (blockIdx.x < 128) {
        const int gt  = tid;              // 0..32767 = BB*NSEG*DD
        const int d   = gt & (DD - 1);
        const int seg = (gt >> 10) & (NSEG - 1);
        const int bb  = gt >> 13;

        float qr, qi;
        phazor_of(p_re[d], p_im[d], qr, qi);
#pragma unroll
        for (int i = 0; i < 4; ++i) csq(qr, qi);      // q = a^16

        const int kk0 = seg * SEG;
        const float2* Sc = S + ((size_t)bb * KK * DD + d);
        float2*       Rc = R + ((size_t)bb * KK * DD + d);

        float2 buf[8];
#pragma unroll
        for (int j = 0; j < 8; ++j) buf[j] = ld8(Sc + (size_t)(kk0 + j) * DD);

        float cr = 0.f, ci = 0.f;
        for (int i = 0; i < SEG; i += 8) {
#pragma unroll
            for (int j = 0; j < 8; ++j) {
                st8(Rc + (size_t)(kk0 + i + j) * DD, make_float2(cr, ci));
                float2 s = buf[j];
                int kn = i + j + 8;
                buf[j] = ld8(Sc + (size_t)(kk0 + (kn < SEG ? kn : SEG - 1)) * DD);
                float nr = fmaf(qr, cr, fmaf(-qi, ci, s.x));
                float ni = fmaf(qr, ci, fmaf( qi, cr, s.y));
                cr = nr; ci = ni;
            }
        }
        st8(T + ((size_t)bb * NSEG + seg) * DD + d, make_float2(cr, ci));
    }

    grid_barrier(bar + 2048, bar + 3072);

    // ---------------- phase 3: segment init + combine + replay ----------------
    const int rel  = k & (SEG - 1);   // wave-uniform
    const int seg3 = k >> 5;          // wave-uniform

    float gr[4], gi[4];
    {
        float4 lrv = *(const float4*)(lc_re + b * DD + d0);
        float4 liv = *(const float4*)(lc_im + b * DD + d0);
        gr[0] = lrv.x; gr[1] = lrv.y; gr[2] = lrv.z; gr[3] = lrv.w;
        gi[0] = liv.x; gi[1] = liv.y; gi[2] = liv.z; gi[3] = liv.w;
        float Qr[4], Qi[4];
#pragma unroll
        for (int q = 0; q < 4; ++q) {
            Qr[q] = ar[q]; Qi[q] = ai[q];
#pragma unroll
            for (int i = 0; i < 9; ++i) csq(Qr[q], Qi[q]);   // a^512
        }
        for (int s = 0; s < seg3; ++s) {                     // <=7 iters, uniform
            const float2* Tp = T + ((size_t)(b * NSEG + s) * DD + d0);
#pragma unroll
            for (int q = 0; q < 4; ++q) {
                float2 t = ld8(Tp + q);
                float nr = fmaf(Qr[q], gr[q], fmaf(-Qi[q], gi[q], t.x));
                float ni = fmaf(Qr[q], gi[q], fmaf( Qi[q], gr[q], t.y));
                gr[q] = nr; gi[q] = ni;
            }
        }
    }

    // C0 = R + (a^16)^rel * g
    float cr[4], ci[4];
    {
        const float2* Rp = R + ((size_t)(b * KK + k) * DD + d0);
#pragma unroll
        for (int q = 0; q < 4; ++q) {
            float qdr = ar[q], qdi = ai[q];
#pragma unroll
            for (int i = 0; i < 4; ++i) csq(qdr, qdi);       // a^16
            float pr = 1.f, pi = 0.f;
            float bpr = qdr, bpi = qdi;
#pragma unroll
            for (int bit = 0; bit < 5; ++bit) {              // (a^16)^rel
                if ((rel >> bit) & 1) {
                    float nr = pr * bpr - pi * bpi;
                    pi = pr * bpi + pi * bpr;
                    pr = nr;
                }
                csq(bpr, bpi);
            }
            float2 r = ld8(Rp + q);
            cr[q] = r.x + pr * gr[q] - pi * gi[q];
            ci[q] = r.y + pr * gi[q] + pi * gr[q];
        }
    }

    // replay chunk (x re-read: same block, same chunk as phase 1 -> local L2 hit;
    // no invalidates ever ran, so those lines are still valid)
    {
        const float* xp = x + xbase;
        float* op = out + xbase;
        float4 xv[16];
#pragma unroll
        for (int j = 0; j < 16; ++j)
            xv[j] = *(const float4*)(xp + (size_t)j * DD);
#pragma unroll
        for (int j = 0; j < 16; ++j) {
            float xs[4] = {xv[j].x, xv[j].y, xv[j].z, xv[j].w};
            float os[4];
#pragma unroll
            for (int q = 0; q < 4; ++q) {
                float nr = fmaf(ar[q], cr[q], fmaf(-ai[q], ci[q], br[q] * xs[q]));
                float ni = fmaf(ar[q], ci[q], fmaf( ai[q], cr[q], bi[q] * xs[q]));
                cr[q] = nr; ci[q] = ni;
                os[q] = nr;
            }
            *(float4*)(op + (size_t)j * DD) = make_float4(os[0], os[1], os[2], os[3]);
        }
    }
}

extern "C" void kernel_launch(void* const* d_in, const int* in_sizes, int n_in,
                              void* d_out, int out_size, void* d_ws, size_t ws_size,
                              hipStream_t stream) {
    const float* x      = (const float*)d_in[0];
    const float* p_re   = (const float*)d_in[1];
    const float* p_im   = (const float*)d_in[2];
    const float* pin_re = (const float*)d_in[3];
    const float* pin_im = (const float*)d_in[4];
    const float* lc_re  = (const float*)d_in[5];
    const float* lc_im  = (const float*)d_in[6];
    float* out = (float*)d_out;

    char* ws = (char*)d_ws;
    float2*   S   = (float2*)(ws);                              // 8 MiB
    float2*   R   = (float2*)(ws + (size_t)8  * 1024 * 1024);   // 8 MiB
    float2*   T   = (float2*)(ws + (size_t)16 * 1024 * 1024);   // 256 KiB
    unsigned* bar = (unsigned*)(ws + (size_t)17 * 1024 * 1024);
    // layout (unsigned units): A0 @0 (32 groups, stride 32 = 128B apart),
    // G0 @1024, A1 @2048, G1 @3072  -> 16 KiB total

    hipMemsetAsync(bar, 0, 16384, stream);   // zero barrier counters

    spiral_fused<<<dim3(NBLK), dim3(256), 0, stream>>>(
        x, p_re, p_im, pin_re, pin_im, lc_re, lc_im, S, R, T, bar, out);
}

// Round 4
// 155.378 us; speedup vs baseline: 4.7585x; 1.0275x over previous
//
#include <hip/hip_runtime.h>

// SpiralConv: g[t] = a*g[t-1] + init*x[t], g[-1]=last_conv; out = Re(g).
//   a = p/|p| * exp(-|p|).
// Fused single-kernel hierarchical chunked scan (CHUNK=16), fence-free
// grid barrier, SINGLE kernel node in the graph (no memset):
//  - Barrier state lives in module-scope __device__ globals (zeroed at load,
//    never touched by the harness's workspace poison) and is MONOTONIC:
//    counters never reset; each leader derives its generation from its own
//    arrival ticket and waits for glob >= (gen+1)*NBLK (wrap-safe compare).
//  - Cross-block data (S, R, T) moves via relaxed AGENT-scope 8B atomics
//    (sc1 -> coherence point, bypasses non-coherent per-XCD L2), so the
//    barrier needs no cache maintenance (no __threadfence storm).
//  - x timesteps 0-7 are stashed in LDS (32 KiB/block) in phase 1 and
//    replayed from LDS in phase 3; timesteps 8-15 are re-read from cache
//    with loads issued BEFORE the segment-init math to hide latency.
// Grid = 1024 blocks x 256 thr = exactly 4 blocks/CU (launch_bounds(256,4),
// LDS 32 KiB <= 160/4 KiB) -> all blocks co-resident -> spin barrier safe.

#define BB 4
#define LL 4096
#define DD 1024
#define CHUNK 16
#define KK 256     // LL/CHUNK
#define SEG 32     // chunks per segment
#define NSEG 8     // KK/SEG
#define NBLK 1024u

// ---- module-scope barrier state: zero-init at load, monotonic forever ----
__device__ unsigned g_grp[2 * 32 * 32];   // [site][group] stride 32 (128 B apart)
__device__ unsigned g_glob[2 * 32];       // [site] padded to 128 B

__device__ __forceinline__ void phazor_of(float pr, float pi, float& ar, float& ai) {
    float mag = sqrtf(pr * pr + pi * pi);
    float s = expf(-mag) / mag;   // phazor = p/|p| * exp(-|p|)
    ar = pr * s;
    ai = pi * s;
}

__device__ __forceinline__ void csq(float& r, float& i) {
    float nr = r * r - i * i;
    i = 2.f * r * i;
    r = nr;
}

// coherence-point (sc1) 8-byte data movement: visible cross-XCD without fences
__device__ __forceinline__ void st8(float2* p, float2 v) {
    __hip_atomic_store(p, v, __ATOMIC_RELAXED, __HIP_MEMORY_SCOPE_AGENT);
}
__device__ __forceinline__ float2 ld8(const float2* p) {
    return __hip_atomic_load((float2*)p, __ATOMIC_RELAXED, __HIP_MEMORY_SCOPE_AGENT);
}

// Fence-free monotonic grid barrier. site = 0 or 1.
// __syncthreads() drains vmcnt -> all sc1 stores are at the coherence point
// before the leader's arrival add; consumers read via sc1 -> no staleness.
__device__ __forceinline__ void grid_barrier(int site) {
    __syncthreads();
    if (threadIdx.x == 0) {
        unsigned* A = &g_grp[site * 1024 + (blockIdx.x >> 5) * 32]; // 32 blocks/group
        unsigned* G = &g_glob[site * 32];
        unsigned a = __hip_atomic_fetch_add(A, 1u,
                        __ATOMIC_RELAXED, __HIP_MEMORY_SCOPE_AGENT);
        unsigned gen = a >> 5;                      // which use of this barrier
        if ((a & 31u) == 31u)
            __hip_atomic_fetch_add(G, 32u,
                        __ATOMIC_RELAXED, __HIP_MEMORY_SCOPE_AGENT);
        unsigned target = (gen + 1u) * NBLK;
        int spins = 0;
        while ((int)(__hip_atomic_load(G, __ATOMIC_RELAXED,
                                       __HIP_MEMORY_SCOPE_AGENT) - target) < 0) {
            __builtin_amdgcn_s_sleep(16);
            if (++spins > (1 << 17)) break;         // safety valve, never hang
        }
    }
    __syncthreads();
}

__global__ __launch_bounds__(256, 4) void spiral_fused(
    const float* __restrict__ x,
    const float* __restrict__ p_re, const float* __restrict__ p_im,
    const float* __restrict__ in_re, const float* __restrict__ in_im,
    const float* __restrict__ lc_re, const float* __restrict__ lc_im,
    float2* __restrict__ S, float2* __restrict__ R, float2* __restrict__ T,
    float* __restrict__ out)
{
    __shared__ float4 xlds[8][256];   // timesteps 0..7 stash, 32 KiB

    const int tid = blockIdx.x * 256 + threadIdx.x;
    const int dq = tid & (DD / 4 - 1);
    const int k  = (tid >> 8) & (KK - 1);
    const int b  = tid >> 16;
    const int d0 = dq * 4;

    // phase-invariant constants: a = phazor(p), binit
    float ar[4], ai[4], br[4], bi[4];
    {
        float4 prv = *(const float4*)(p_re + d0);
        float4 piv = *(const float4*)(p_im + d0);
        float4 brv = *(const float4*)(in_re + d0);
        float4 biv = *(const float4*)(in_im + d0);
        float prs[4] = {prv.x, prv.y, prv.z, prv.w};
        float pis[4] = {piv.x, piv.y, piv.z, piv.w};
        br[0] = brv.x; br[1] = brv.y; br[2] = brv.z; br[3] = brv.w;
        bi[0] = biv.x; bi[1] = biv.y; bi[2] = biv.z; bi[3] = biv.w;
#pragma unroll
        for (int q = 0; q < 4; ++q) phazor_of(prs[q], pis[q], ar[q], ai[q]);
    }

    const size_t xbase = (size_t)(b * LL + k * CHUNK) * DD + d0;

    // ---------------- phase 1: chunk-local scan, zero init ----------------
    {
        const float* xp = x + xbase;
        float4 xv[16];
#pragma unroll
        for (int j = 0; j < 16; ++j)
            xv[j] = *(const float4*)(xp + (size_t)j * DD);

        // stash first half for phase-3 replay (conflict-free: lane-contiguous)
#pragma unroll
        for (int j = 0; j < 8; ++j)
            xlds[j][threadIdx.x] = xv[j];

        float sr[4] = {0.f, 0.f, 0.f, 0.f};
        float si[4] = {0.f, 0.f, 0.f, 0.f};
#pragma unroll
        for (int j = 0; j < 16; ++j) {
            float xs[4] = {xv[j].x, xv[j].y, xv[j].z, xv[j].w};
#pragma unroll
            for (int q = 0; q < 4; ++q) {
                float nr = fmaf(ar[q], sr[q], fmaf(-ai[q], si[q], br[q] * xs[q]));
                float ni = fmaf(ar[q], si[q], fmaf( ai[q], sr[q], bi[q] * xs[q]));
                sr[q] = nr; si[q] = ni;
            }
        }
        float2* Sp = S + ((size_t)(b * KK + k) * DD + d0);
#pragma unroll
        for (int q = 0; q < 4; ++q)
            st8(Sp + q, make_float2(sr[q], si[q]));
    }

    grid_barrier(0);

    // ---------------- phase 2: segment-relative scans (first 128 blocks) ----------------
    if (blockIdx.x < 128) {
        const int gt  = tid;              // 0..32767 = BB*NSEG*DD
        const int d   = gt & (DD - 1);
        const int seg = (gt >> 10) & (NSEG - 1);
        const int bb  = gt >> 13;

        float qr, qi;
        phazor_of(p_re[d], p_im[d], qr, qi);
#pragma unroll
        for (int i = 0; i < 4; ++i) csq(qr, qi);      // q = a^16

        const int kk0 = seg * SEG;
        const float2* Sc = S + ((size_t)bb * KK * DD + d);
        float2*       Rc = R + ((size_t)bb * KK * DD + d);

        float2 buf[8];
#pragma unroll
        for (int j = 0; j < 8; ++j) buf[j] = ld8(Sc + (size_t)(kk0 + j) * DD);

        float cr = 0.f, ci = 0.f;
        for (int i = 0; i < SEG; i += 8) {
#pragma unroll
            for (int j = 0; j < 8; ++j) {
                st8(Rc + (size_t)(kk0 + i + j) * DD, make_float2(cr, ci));
                float2 s = buf[j];
                int kn = i + j + 8;
                buf[j] = ld8(Sc + (size_t)(kk0 + (kn < SEG ? kn : SEG - 1)) * DD);
                float nr = fmaf(qr, cr, fmaf(-qi, ci, s.x));
                float ni = fmaf(qr, ci, fmaf( qi, cr, s.y));
                cr = nr; ci = ni;
            }
        }
        st8(T + ((size_t)bb * NSEG + seg) * DD + d, make_float2(cr, ci));
    }

    grid_barrier(1);

    // ---------------- phase 3: segment init + combine + replay ----------------
    const int rel  = k & (SEG - 1);   // wave-uniform
    const int seg3 = k >> 5;          // wave-uniform

    // issue second-half x loads NOW; latency hides under the scan/combine math
    float4 xv2[8];
    {
        const float* xp = x + xbase;
#pragma unroll
        for (int j = 0; j < 8; ++j)
            xv2[j] = *(const float4*)(xp + (size_t)(8 + j) * DD);
    }

    float gr[4], gi[4];
    {
        float4 lrv = *(const float4*)(lc_re + b * DD + d0);
        float4 liv = *(const float4*)(lc_im + b * DD + d0);
        gr[0] = lrv.x; gr[1] = lrv.y; gr[2] = lrv.z; gr[3] = lrv.w;
        gi[0] = liv.x; gi[1] = liv.y; gi[2] = liv.z; gi[3] = liv.w;
        float Qr[4], Qi[4];
#pragma unroll
        for (int q = 0; q < 4; ++q) {
            Qr[q] = ar[q]; Qi[q] = ai[q];
#pragma unroll
            for (int i = 0; i < 9; ++i) csq(Qr[q], Qi[q]);   // a^512
        }
        for (int s = 0; s < seg3; ++s) {                     // <=7 iters, uniform
            const float2* Tp = T + ((size_t)(b * NSEG + s) * DD + d0);
#pragma unroll
            for (int q = 0; q < 4; ++q) {
                float2 t = ld8(Tp + q);
                float nr = fmaf(Qr[q], gr[q], fmaf(-Qi[q], gi[q], t.x));
                float ni = fmaf(Qr[q], gi[q], fmaf( Qi[q], gr[q], t.y));
                gr[q] = nr; gi[q] = ni;
            }
        }
    }

    // C0 = R + (a^16)^rel * g
    float cr[4], ci[4];
    {
        const float2* Rp = R + ((size_t)(b * KK + k) * DD + d0);
#pragma unroll
        for (int q = 0; q < 4; ++q) {
            float qdr = ar[q], qdi = ai[q];
#pragma unroll
            for (int i = 0; i < 4; ++i) csq(qdr, qdi);       // a^16
            float pr = 1.f, pi = 0.f;
            float bpr = qdr, bpi = qdi;
#pragma unroll
            for (int bit = 0; bit < 5; ++bit) {              // (a^16)^rel
                if ((rel >> bit) & 1) {
                    float nr = pr * bpr - pi * bpi;
                    pi = pr * bpi + pi * bpr;
                    pr = nr;
                }
                csq(bpr, bpi);
            }
            float2 r = ld8(Rp + q);
            cr[q] = r.x + pr * gr[q] - pi * gi[q];
            ci[q] = r.y + pr * gi[q] + pi * gr[q];
        }
    }

    // replay: timesteps 0..7 from LDS, 8..15 from the early global loads
    {
        float* op = out + xbase;
#pragma unroll
        for (int j = 0; j < 8; ++j) {
            float4 xj = xlds[j][threadIdx.x];
            float xs[4] = {xj.x, xj.y, xj.z, xj.w};
            float os[4];
#pragma unroll
            for (int q = 0; q < 4; ++q) {
                float nr = fmaf(ar[q], cr[q], fmaf(-ai[q], ci[q], br[q] * xs[q]));
                float ni = fmaf(ar[q], ci[q], fmaf( ai[q], cr[q], bi[q] * xs[q]));
                cr[q] = nr; ci[q] = ni;
                os[q] = nr;
            }
            *(float4*)(op + (size_t)j * DD) = make_float4(os[0], os[1], os[2], os[3]);
        }
#pragma unroll
        for (int j = 0; j < 8; ++j) {
            float xs[4] = {xv2[j].x, xv2[j].y, xv2[j].z, xv2[j].w};
            float os[4];
#pragma unroll
            for (int q = 0; q < 4; ++q) {
                float nr = fmaf(ar[q], cr[q], fmaf(-ai[q], ci[q], br[q] * xs[q]));
                float ni = fmaf(ar[q], ci[q], fmaf( ai[q], cr[q], bi[q] * xs[q]));
                cr[q] = nr; ci[q] = ni;
                os[q] = nr;
            }
            *(float4*)(op + (size_t)(8 + j) * DD) = make_float4(os[0], os[1], os[2], os[3]);
        }
    }
}

extern "C" void kernel_launch(void* const* d_in, const int* in_sizes, int n_in,
                              void* d_out, int out_size, void* d_ws, size_t ws_size,
                              hipStream_t stream) {
    const float* x      = (const float*)d_in[0];
    const float* p_re   = (const float*)d_in[1];
    const float* p_im   = (const float*)d_in[2];
    const float* pin_re = (const float*)d_in[3];
    const float* pin_im = (const float*)d_in[4];
    const float* lc_re  = (const float*)d_in[5];
    const float* lc_im  = (const float*)d_in[6];
    float* out = (float*)d_out;

    char* ws = (char*)d_ws;
    float2* S = (float2*)(ws);                              // 8 MiB
    float2* R = (float2*)(ws + (size_t)8  * 1024 * 1024);   // 8 MiB
    float2* T = (float2*)(ws + (size_t)16 * 1024 * 1024);   // 256 KiB

    // single kernel node: barrier state is module-scope + monotonic, no memset
    spiral_fused<<<dim3(NBLK), dim3(256), 0, stream>>>(
        x, p_re, p_im, pin_re, pin_im, lc_re, lc_im, S, R, T, out);
}